// Round 2
// baseline (863.231 us; speedup 1.0000x reference)
//
#include <hip/hip_runtime.h>
#include <hip/hip_bf16.h>

#define B_ 64
#define S_ 720
#define C_ 321
#define P_ 336
#define SP 736          // S padded to multiple of 32 (zeros)
#define WIN 25
#define PADW 12
#define NTILE 48        // P per block (7 blocks/channel) -> 2247 blocks, ~8/CU
#define NTPC 7
#define KSTEPS 23       // 736/32
#define CT 8            // channels per pass0 block
#define AQ_PER_MAT 1890048   // uint4 per matrix: 321*64*92

typedef __bf16 bf16x8 __attribute__((ext_vector_type(8)));
typedef float f32x4 __attribute__((ext_vector_type(4)));

__device__ __forceinline__ unsigned short f2bf(float f) {
  unsigned int u = __builtin_bit_cast(unsigned int, f);
  u += 0x7FFFu + ((u >> 16) & 1u);   // RNE
  return (unsigned short)(u >> 16);
}

// Pass 0 (coalesced): block = (ctile, b). Loads x[b, :, c0:c0+8] with 32B
// row segments, LDS-transposes, sliding-window avgpool per channel, writes
// resT/seaT rows [C][B][SP] as contiguous 1472B runs.
__global__ __launch_bounds__(256) void pass0_decomp(
    const float* __restrict__ x,
    uint4* __restrict__ resQ,
    uint4* __restrict__ seaQ) {
  __shared__ float xs[CT][745];                   // [c][PADW + s], +1 pad (745%32=9)
  __shared__ unsigned short obuf[2 * CT * SP];    // [m][c][s] bf16
  int c0 = blockIdx.x * CT;
  int b = blockIdx.y;
  int t = threadIdx.x;

  // halos: zero xs[:, 0:12) and [732:744); zero obuf K-tail s in [720,736)
  if (t < CT * 24) {
    int c = t / 24, h = t % 24;
    xs[c][h < 12 ? h : h + 720] = 0.f;
  }
  {
    int m = t >> 7, c = (t >> 4) & 7, s = 720 + (t & 15);
    obuf[(m * CT + c) * SP + s] = 0;
  }
  // load: lane c fastest (consecutive addresses within a row segment)
  {
    int c = t & 7;
    int svalid = (c0 + c < C_);
    for (int p = 0; p < 23; ++p) {
      int s = (t >> 3) + p * 32;
      if (s < S_ && svalid) xs[c][PADW + s] = x[(b * S_ + s) * C_ + c0 + c];
    }
  }
  __syncthreads();
  // sliding window: thread = (c, chunk of 23 outputs)
  {
    int c = t & 7;
    int s0 = (t >> 3) * 23;
    int s1 = s0 + 23; if (s1 > S_) s1 = S_;
    float wsum = 0.f;
#pragma unroll
    for (int j = 0; j < WIN; ++j) wsum += xs[c][s0 + j];
    for (int s = s0; s < s1; ++s) {
      float sea = wsum * (1.0f / WIN);
      float res = xs[c][s + PADW] - sea;
      obuf[c * SP + s] = f2bf(res);
      obuf[(CT + c) * SP + s] = f2bf(sea);
      wsum += xs[c][s + WIN] - xs[c][s];
    }
  }
  __syncthreads();
  // writeout: 16 rows (2m x 8c) x 92 uint4, fully coalesced
  const uint4* ob = (const uint4*)obuf;
  for (int i = t; i < 2 * CT * 92; i += 256) {
    int row = i / 92;
    int off = i - row * 92;
    int c = row & 7;
    int m = row >> 3;
    if (c0 + c < C_) {
      uint4* dst = m ? seaQ : resQ;
      dst[((c0 + c) * B_ + b) * 92 + off] = ob[row * 92 + off];
    }
  }
}

// GEMM: block = (channel c, 48-wide p-tile). 7 tiles/channel -> 2247 blocks
// (~8.8/CU). LDS 18.1KB + VGPR<=64 => 8 blocks/CU resident; unsynchronized
// blocks interleave their load bursts so the HBM pipe stays saturated.
// Software-pipelined: global loads for iter ks+1 issued after the LDS-ready
// barrier, overlapping the ds_read+MFMA phase of iter ks. LDS rows padded to
// 80B (2-way banks = free).
__global__ __launch_bounds__(256, 8) void gemm_fused(
    const uint4* __restrict__ abase,   // resT; seaT at +AQ_PER_MAT uint4
    const float4* __restrict__ wR,
    const float4* __restrict__ wT,
    const float* __restrict__ bR,
    const float* __restrict__ bT,
    float* __restrict__ out) {
  __shared__ __align__(16) unsigned char lds[10240 + 7680 + 192];
  unsigned char* ldsA = lds;                       // [2][64 rows][80B] (32 bf16 + pad)
  unsigned char* ldsB = lds + 10240;               // [2][48 rows][80B]
  float* bsum = (float*)(lds + 10240 + 7680);      // 48 floats

  int blk = blockIdx.x;
  int c = blk / NTPC;
  int nt = blk - c * NTPC;
  int p0 = nt * NTILE;
  int t = threadIdx.x;
  int w = t >> 6;
  int lane = t & 63;
  int col = lane & 15;
  int quad = lane >> 4;

  if (t < NTILE) bsum[t] = bR[c * P_ + p0 + t] + bT[c * P_ + p0 + t];

  // A staging: 512 x 16B chunks, 2 per thread
  int aOffG[2], aOffL[2];
#pragma unroll
  for (int i = 0; i < 2; ++i) {
    int idx = i * 256 + t;
    int m = idx >> 8;             // 0=res, 1=season (wave-uniform)
    int r = (idx >> 2) & 63;      // batch row
    int k16 = idx & 3;            // 16B chunk within 32-k row
    aOffG[i] = m * AQ_PER_MAT + c * 5888 + r * 92 + k16;   // uint4 units
    aOffL[i] = m * 5120 + r * 80 + k16 * 16;               // bytes
  }
  // B staging: 768 float4 (fp32) chunks, 3 per thread -> bf16 LDS
  int bOffG[3], bOffL[3], bK4[3], bM[3];
#pragma unroll
  for (int i = 0; i < 3; ++i) {
    int idx = i * 256 + t;
    int m = idx / 384;
    int rem = idx - m * 384;
    int r = rem >> 3;             // p row 0..47
    int k4 = rem & 7;             // float4 within 32-k row
    bM[i] = m;
    bK4[i] = k4;
    bOffG[i] = c * 60480 + (p0 + r) * 180 + k4;            // float4 units
    bOffL[i] = m * 3840 + r * 80 + k4 * 8;                 // bytes
  }

  f32x4 acc[3];
#pragma unroll
  for (int i = 0; i < 3; ++i) acc[i] = (f32x4){0.f, 0.f, 0.f, 0.f};

  int aFragOff = (w * 16 + col) * 80 + quad * 16;

  // ---- prologue: load iter 0 into registers ----
  uint4 av[2];
  float4 bv[3];
#pragma unroll
  for (int i = 0; i < 2; ++i) av[i] = abase[aOffG[i]];
#pragma unroll
  for (int i = 0; i < 3; ++i) {
    float4 v = {0.f, 0.f, 0.f, 0.f};
    if (bK4[i] * 4 < S_) {
      const float4* src = bM[i] ? wT : wR;
      v = src[bOffG[i]];
    }
    bv[i] = v;
  }

  for (int ks = 0; ks < KSTEPS; ++ks) {
    __syncthreads();   // prev iter's frag reads done (also orders bsum on ks=0)
#pragma unroll
    for (int i = 0; i < 2; ++i) *(uint4*)(ldsA + aOffL[i]) = av[i];
#pragma unroll
    for (int i = 0; i < 3; ++i) {
      ushort4 pk;
      pk.x = f2bf(bv[i].x); pk.y = f2bf(bv[i].y);
      pk.z = f2bf(bv[i].z); pk.w = f2bf(bv[i].w);
      *(ushort4*)(ldsB + bOffL[i]) = pk;
    }
    __syncthreads();
    // ---- prefetch iter ks+1 (latency overlaps MFMA below) ----
    if (ks + 1 < KSTEPS) {
      int kn = ks + 1;
#pragma unroll
      for (int i = 0; i < 2; ++i) av[i] = abase[aOffG[i] + kn * 4];
#pragma unroll
      for (int i = 0; i < 3; ++i) {
        float4 v = {0.f, 0.f, 0.f, 0.f};
        if (kn * 32 + bK4[i] * 4 < S_) {
          const float4* src = bM[i] ? wT : wR;
          v = src[bOffG[i] + kn * 8];
        }
        bv[i] = v;
      }
    }
    // ---- compute on current LDS tile ----
    bf16x8 aR = *(const bf16x8*)(ldsA + aFragOff);
    bf16x8 aS = *(const bf16x8*)(ldsA + 5120 + aFragOff);
#pragma unroll
    for (int tt = 0; tt < 3; ++tt) {
      int bo = (tt * 16 + col) * 80 + quad * 16;
      bf16x8 bRf = *(const bf16x8*)(ldsB + bo);
      bf16x8 bTf = *(const bf16x8*)(ldsB + 3840 + bo);
      acc[tt] = __builtin_amdgcn_mfma_f32_16x16x32_bf16(aR, bRf, acc[tt], 0, 0, 0);
      acc[tt] = __builtin_amdgcn_mfma_f32_16x16x32_bf16(aS, bTf, acc[tt], 0, 0, 0);
    }
  }

  // Epilogue: C/D map col=lane&15 (p), row=quad*4+reg (b). r outer, tt inner
  // so each (brow) emits 3 ascending 64B segments (192B run) for L2 merge.
#pragma unroll
  for (int r = 0; r < 4; ++r) {
    int brow = w * 16 + quad * 4 + r;
#pragma unroll
    for (int tt = 0; tt < 3; ++tt) {
      int p = p0 + tt * 16 + col;
      out[(brow * C_ + c) * P_ + p] = acc[tt][r] + bsum[tt * 16 + col];
    }
  }
}

extern "C" void kernel_launch(void* const* d_in, const int* in_sizes, int n_in,
                              void* d_out, int out_size, void* d_ws, size_t ws_size,
                              hipStream_t stream) {
  const float* x = (const float*)d_in[0];
  const float4* wR = (const float4*)d_in[1];
  const float* bR = (const float*)d_in[2];
  const float4* wT = (const float4*)d_in[3];
  const float* bT = (const float*)d_in[4];
  float* out = (float*)d_out;

  uint4* resQ = (uint4*)d_ws;                    // [C][B][92] uint4 (bf16 rows)
  uint4* seaQ = resQ + AQ_PER_MAT;

  dim3 g0((C_ + CT - 1) / CT, B_);               // 41 x 64
  pass0_decomp<<<g0, 256, 0, stream>>>(x, resQ, seaQ);
  gemm_fused<<<C_ * NTPC, 256, 0, stream>>>((const uint4*)d_ws, wR, wT, bR, bT, out);
}

// Round 4
// 735.347 us; speedup vs baseline: 1.1739x; 1.1739x over previous
//
#include <hip/hip_runtime.h>
#include <hip/hip_bf16.h>

#define B_ 64
#define S_ 720
#define C_ 321
#define P_ 336
#define SP 736          // S padded to multiple of 32 (zeros)
#define WIN 25
#define PADW 12
#define NTILE 112       // P per block (3 blocks/channel)
#define NTPC 3
#define KSTEPS 23       // 736/32
#define CT 8            // channels per pass0 block
#define AQ_PER_MAT 1890048   // uint4 per matrix: 321*64*92

typedef __bf16 bf16x8 __attribute__((ext_vector_type(8)));
typedef float f32x4 __attribute__((ext_vector_type(4)));

__device__ __forceinline__ unsigned short f2bf(float f) {
  unsigned int u = __builtin_bit_cast(unsigned int, f);
  u += 0x7FFFu + ((u >> 16) & 1u);   // RNE
  return (unsigned short)(u >> 16);
}

// Pass 0 (coalesced): block = (ctile, b). Loads x[b, :, c0:c0+8] with 32B
// row segments, LDS-transposes, sliding-window avgpool per channel, writes
// resT/seaT rows [C][B][SP] as contiguous 1472B runs.
__global__ __launch_bounds__(256) void pass0_decomp(
    const float* __restrict__ x,
    uint4* __restrict__ resQ,
    uint4* __restrict__ seaQ) {
  __shared__ float xs[CT][745];                   // [c][PADW + s], +1 pad (745%32=9)
  __shared__ unsigned short obuf[2 * CT * SP];    // [m][c][s] bf16
  int c0 = blockIdx.x * CT;
  int b = blockIdx.y;
  int t = threadIdx.x;

  // halos: zero xs[:, 0:12) and [732:744); zero obuf K-tail s in [720,736)
  if (t < CT * 24) {
    int c = t / 24, h = t % 24;
    xs[c][h < 12 ? h : h + 720] = 0.f;
  }
  {
    int m = t >> 7, c = (t >> 4) & 7, s = 720 + (t & 15);
    obuf[(m * CT + c) * SP + s] = 0;
  }
  // load: lane c fastest (consecutive addresses within a row segment)
  {
    int c = t & 7;
    int svalid = (c0 + c < C_);
    for (int p = 0; p < 23; ++p) {
      int s = (t >> 3) + p * 32;
      if (s < S_ && svalid) xs[c][PADW + s] = x[(b * S_ + s) * C_ + c0 + c];
    }
  }
  __syncthreads();
  // sliding window: thread = (c, chunk of 23 outputs)
  {
    int c = t & 7;
    int s0 = (t >> 3) * 23;
    int s1 = s0 + 23; if (s1 > S_) s1 = S_;
    float wsum = 0.f;
#pragma unroll
    for (int j = 0; j < WIN; ++j) wsum += xs[c][s0 + j];
    for (int s = s0; s < s1; ++s) {
      float sea = wsum * (1.0f / WIN);
      float res = xs[c][s + PADW] - sea;
      obuf[c * SP + s] = f2bf(res);
      obuf[(CT + c) * SP + s] = f2bf(sea);
      wsum += xs[c][s + WIN] - xs[c][s];
    }
  }
  __syncthreads();
  // writeout: 16 rows (2m x 8c) x 92 uint4, fully coalesced
  const uint4* ob = (const uint4*)obuf;
  for (int i = t; i < 2 * CT * 92; i += 256) {
    int row = i / 92;
    int off = i - row * 92;
    int c = row & 7;
    int m = row >> 3;
    if (c0 + c < C_) {
      uint4* dst = m ? seaQ : resQ;
      dst[((c0 + c) * B_ + b) * 92 + off] = ob[row * 92 + off];
    }
  }
}

// GEMM: block = (channel c, 112-wide p-tile). T3/T4 pipeline: raw s_barrier
// + counted vmcnt (never drained to 0 in steady state). Two register sets:
// the set consumed at iter ks was issued at iter ks-2, so ~2 full iterations
// of MFMA+staging hide the HBM latency. All iterations issue exactly 9 loads
// (OOB B k-chunks load a clamped valid address; they multiply A's zero pad
// k in [720,736), so the result is exact) keeping vmcnt arithmetic constant.
__global__ __launch_bounds__(256) void gemm_fused(
    const uint4* __restrict__ abase,   // resT; seaT at +AQ_PER_MAT uint4
    const float4* __restrict__ wR,
    const float4* __restrict__ wT,
    const float* __restrict__ bR,
    const float* __restrict__ bT,
    float* __restrict__ out) {
  __shared__ __align__(16) unsigned char lds[10240 + 17920];
  unsigned char* ldsA = lds;                       // [2][64 rows][80B] (32 bf16 + pad)
  unsigned char* ldsB = lds + 10240;               // [2][112 rows][80B]

  int blk = blockIdx.x;
  int c = blk / NTPC;
  int nt = blk - c * NTPC;
  int p0 = nt * NTILE;
  int t = threadIdx.x;
  int w = t >> 6;
  int lane = t & 63;
  int col = lane & 15;
  int quad = lane >> 4;

  // A staging: 512 x 16B chunks, 2 per thread
  int aOffG[2], aOffL[2];
#pragma unroll
  for (int i = 0; i < 2; ++i) {
    int idx = i * 256 + t;
    int m = idx >> 8;             // 0=res, 1=season
    int r = (idx >> 2) & 63;      // batch row
    int k16 = idx & 3;            // 16B chunk within 32-k row
    aOffG[i] = m * AQ_PER_MAT + c * 5888 + r * 92 + k16;   // uint4 units
    aOffL[i] = m * 5120 + r * 80 + k16 * 16;               // bytes
  }
  // B staging: 1792 float4 (fp32) chunks, 7 per thread -> bf16 LDS
  int bOffG[7], bOffL[7], bLim[7], bM[7];
#pragma unroll
  for (int i = 0; i < 7; ++i) {
    int idx = i * 256 + t;
    int m = idx / 896;
    int rem = idx - m * 896;
    int r = rem >> 3;             // p row 0..111
    int k4 = rem & 7;             // float4 within 32-k row
    bM[i] = m;
    bLim[i] = S_ - k4 * 4;        // chunk valid iff kn*32 < bLim
    bOffG[i] = c * 60480 + (p0 + r) * 180 + k4;            // float4 units
    bOffL[i] = m * 8960 + r * 80 + k4 * 8;                 // bytes
  }

  f32x4 acc[7];
#pragma unroll
  for (int i = 0; i < 7; ++i) acc[i] = (f32x4){0.f, 0.f, 0.f, 0.f};

  int aFragOff = (w * 16 + col) * 80 + quad * 16;

  uint4 av0[2], av1[2];
  float4 bv0[7], bv1[7];

  // 9 loads per set; OOB B chunks clamp to kn=0 (valid, finite; hits A=0 pad)
#define ISSUE(av, bv, kn)                                                     \
  {                                                                           \
    _Pragma("unroll")                                                         \
    for (int i = 0; i < 2; ++i) av[i] = abase[aOffG[i] + (kn) * 4];           \
    _Pragma("unroll")                                                         \
    for (int i = 0; i < 7; ++i) {                                             \
      const float4* s = bM[i] ? wT : wR;                                      \
      int off = bOffG[i] + (((kn) * 32 < bLim[i]) ? (kn) * 8 : 0);            \
      bv[i] = s[off];                                                         \
    }                                                                         \
  }

  // barrier(prev frag reads done) -> LDS write -> issue ks+2 -> barrier -> MFMA
#define STAGE_AND_COMPUTE(av, bv, kn_next, doIssue)                           \
  {                                                                           \
    __builtin_amdgcn_s_barrier();                                             \
    _Pragma("unroll")                                                         \
    for (int i = 0; i < 2; ++i) *(uint4*)(ldsA + aOffL[i]) = av[i];           \
    _Pragma("unroll")                                                         \
    for (int i = 0; i < 7; ++i) {                                             \
      ushort4 pk;                                                             \
      pk.x = f2bf(bv[i].x); pk.y = f2bf(bv[i].y);                             \
      pk.z = f2bf(bv[i].z); pk.w = f2bf(bv[i].w);                             \
      *(ushort4*)(ldsB + bOffL[i]) = pk;                                      \
    }                                                                         \
    if (doIssue) ISSUE(av, bv, kn_next)                                       \
    asm volatile("s_waitcnt lgkmcnt(0)" ::: "memory");                        \
    __builtin_amdgcn_sched_barrier(0);                                        \
    __builtin_amdgcn_s_barrier();                                             \
    __builtin_amdgcn_sched_barrier(0);                                        \
    bf16x8 aR = *(const bf16x8*)(ldsA + aFragOff);                            \
    bf16x8 aS = *(const bf16x8*)(ldsA + 5120 + aFragOff);                     \
    _Pragma("unroll")                                                         \
    for (int tt = 0; tt < 7; ++tt) {                                          \
      int bo = (tt * 16 + col) * 80 + quad * 16;                              \
      bf16x8 bRf = *(const bf16x8*)(ldsB + bo);                               \
      bf16x8 bTf = *(const bf16x8*)(ldsB + 8960 + bo);                        \
      acc[tt] = __builtin_amdgcn_mfma_f32_16x16x32_bf16(aR, bRf, acc[tt], 0, 0, 0); \
      acc[tt] = __builtin_amdgcn_mfma_f32_16x16x32_bf16(aS, bTf, acc[tt], 0, 0, 0); \
    }                                                                         \
  }

  // ---- prologue: two K-steps in flight; set0's 9 loads are oldest ----
  ISSUE(av0, bv0, 0)
  asm volatile("" ::: "memory");   // keep set0/set1 issue order (vmcnt FIFO)
  ISSUE(av1, bv1, 1)

#pragma unroll 1
  for (int ks = 0; ks + 2 < KSTEPS; ks += 2) {
    asm volatile("s_waitcnt vmcnt(9)" ::: "memory");  // set0 landed, set1 in flight
    __builtin_amdgcn_sched_barrier(0);
    STAGE_AND_COMPUTE(av0, bv0, ks + 2, true)
    asm volatile("s_waitcnt vmcnt(9)" ::: "memory");  // set1 landed, set0 in flight
    __builtin_amdgcn_sched_barrier(0);
    STAGE_AND_COMPUTE(av1, bv1, ks + 3, (ks + 3 < KSTEPS))
  }
  // final K-step (ks = 22, set0)
  asm volatile("s_waitcnt vmcnt(0)" ::: "memory");
  __builtin_amdgcn_sched_barrier(0);
  STAGE_AND_COMPUTE(av0, bv0, 0, false)

#undef ISSUE
#undef STAGE_AND_COMPUTE

  // Epilogue: bias loaded here (not pre-loop LDS) to keep loop vmcnt exact.
  // C/D map col=lane&15 (p), row=quad*4+reg (b). r outer, tt inner so each
  // brow emits 7 ascending 64B segments (448B run) for L2 merge.
  float bias[7];
#pragma unroll
  for (int tt = 0; tt < 7; ++tt) {
    int p = c * P_ + p0 + tt * 16 + col;
    bias[tt] = bR[p] + bT[p];
  }
#pragma unroll
  for (int r = 0; r < 4; ++r) {
    int brow = w * 16 + quad * 4 + r;
#pragma unroll
    for (int tt = 0; tt < 7; ++tt) {
      int p = p0 + tt * 16 + col;
      out[(brow * C_ + c) * P_ + p] = acc[tt][r] + bias[tt];
    }
  }
}

extern "C" void kernel_launch(void* const* d_in, const int* in_sizes, int n_in,
                              void* d_out, int out_size, void* d_ws, size_t ws_size,
                              hipStream_t stream) {
  const float* x = (const float*)d_in[0];
  const float4* wR = (const float4*)d_in[1];
  const float* bR = (const float*)d_in[2];
  const float4* wT = (const float4*)d_in[3];
  const float* bT = (const float*)d_in[4];
  float* out = (float*)d_out;

  uint4* resQ = (uint4*)d_ws;                    // [C][B][92] uint4 (bf16 rows)
  uint4* seaQ = resQ + AQ_PER_MAT;

  dim3 g0((C_ + CT - 1) / CT, B_);               // 41 x 64
  pass0_decomp<<<g0, 256, 0, stream>>>(x, resQ, seaQ);
  gemm_fused<<<C_ * NTPC, 256, 0, stream>>>((const uint4*)d_ws, wR, wT, bR, bT, out);
}